// Round 10
// baseline (374.945 us; speedup 1.0000x reference)
//
#include <hip/hip_runtime.h>

typedef __attribute__((ext_vector_type(8))) short bf16x8;
typedef __attribute__((ext_vector_type(4))) float f32x4;

#define RFL(v) __builtin_amdgcn_readfirstlane(v)

constexpr int D = 64;
constexpr int SEG = 64;   // relation-segment padding granule = edges per wave

__device__ inline unsigned short f2bf(float f) {  // RNE fp32->bf16
  unsigned u = __float_as_uint(f);
  u += 0x7fff + ((u >> 16) & 1);
  return (unsigned short)(u >> 16);
}
__device__ inline float bflo(unsigned u) { return __uint_as_float(u << 16); }
__device__ inline float bfhi(unsigned u) { return __uint_as_float(u & 0xffff0000u); }

// ---- counting: per-block relation histogram -> bcnt[r*nbE+b]; deg atomics ----
__global__ __launch_bounds__(256) void count_kernel(
    const int* __restrict__ dst, const int* __restrict__ et,
    int* __restrict__ bcnt, int* __restrict__ deg, int E, int R, int nbE) {
  __shared__ int lh[128];
  int t = threadIdx.x;
  if (t < 128) lh[t] = 0;
  __syncthreads();
  int e = blockIdx.x * 256 + t;
  if (e < E) {
    atomicAdd(&deg[dst[e]], 1);
    atomicAdd(&lh[et[e]], 1);
  }
  __syncthreads();
  if (t < R) bcnt[t * nbE + blockIdx.x] = lh[t];  // no global hist atomics
}

// ---- generic 3-phase exclusive scan: A) block sums, B) scan sums, C) rescan ----
__global__ __launch_bounds__(256) void scanA_kernel(
    const int* __restrict__ arr, int* __restrict__ bsum, int n) {
  __shared__ int s[256];
  int t = threadIdx.x;
  int i = blockIdx.x * 256 + t;
  s[t] = (i < n) ? arr[i] : 0;
  __syncthreads();
  for (int o = 128; o > 0; o >>= 1) {
    if (t < o) s[t] += s[t + o];
    __syncthreads();
  }
  if (t == 0) bsum[blockIdx.x] = s[0];
}

__global__ __launch_bounds__(256) void scanB_kernel(int* __restrict__ bsum, int nb) {
  __shared__ int s[256];
  __shared__ int carry;
  int t = threadIdx.x;
  if (t == 0) carry = 0;
  __syncthreads();
  for (int base = 0; base < nb; base += 256) {
    int i = base + t;
    int v = (i < nb) ? bsum[i] : 0;
    s[t] = v;
    __syncthreads();
    for (int o = 1; o < 256; o <<= 1) {
      int u = (t >= o) ? s[t - o] : 0;
      __syncthreads();
      s[t] += u;
      __syncthreads();
    }
    if (i < nb) bsum[i] = carry + s[t] - v;   // exclusive
    __syncthreads();
    if (t == 0) carry += s[255];
    __syncthreads();
  }
}

// writes pref[i] (exclusive) and pref[n] = total
__global__ __launch_bounds__(256) void scanC_pref_kernel(
    const int* __restrict__ arr, const int* __restrict__ bsum,
    int* __restrict__ pref, int n) {
  __shared__ int s[256];
  int t = threadIdx.x;
  int i = blockIdx.x * 256 + t;
  int v = (i < n) ? arr[i] : 0;
  s[t] = v;
  __syncthreads();
  for (int o = 1; o < 256; o <<= 1) {
    int u = (t >= o) ? s[t - o] : 0;
    __syncthreads();
    s[t] += u;
    __syncthreads();
  }
  int excl = bsum[blockIdx.x] + s[t] - v;
  if (i < n) pref[i] = excl;
  if (i == n - 1) pref[n] = excl + v;
}

// deg variant: writes dstoff (N+1) and working copy cur2
__global__ __launch_bounds__(256) void scanC_deg_kernel(
    const int* __restrict__ deg, const int* __restrict__ bsum,
    int* __restrict__ dstoff, int* __restrict__ cur2, int N) {
  __shared__ int s[256];
  int t = threadIdx.x;
  int i = blockIdx.x * 256 + t;
  int v = (i < N) ? deg[i] : 0;
  s[t] = v;
  __syncthreads();
  for (int o = 1; o < 256; o <<= 1) {
    int u = (t >= o) ? s[t - o] : 0;
    __syncthreads();
    s[t] += u;
    __syncthreads();
  }
  int excl = bsum[blockIdx.x] + s[t] - v;
  if (i < N) { dstoff[i] = excl; cur2[i] = excl; }
  if (i == N - 1) dstoff[N] = excl + v;
}

// ---- padded relation cursors from bcnt-scan boundary values ----
__global__ void prefix_kernel(const int* __restrict__ prefE,
                              int* __restrict__ cursor, int nbE, int R) {
  __shared__ int sc[128];
  int l = threadIdx.x;
  int c = 0;
  if (l < R) {
    int tot = prefE[(l + 1) * nbE] - prefE[l * nbE];
    c = (tot + SEG - 1) & ~(SEG - 1);
  }
  sc[l] = c;
  __syncthreads();
  for (int ofs = 1; ofs < 128; ofs <<= 1) {
    int v = (l >= ofs) ? sc[l - ofs] : 0;
    __syncthreads();
    sc[l] += v;
    __syncthreads();
  }
  if (l < R) cursor[l] = sc[l] - c;
}

// ---- wave -> relation table (wave-uniform lookup for msg_kernel) ----
__global__ void wrel_kernel(const int* __restrict__ prefE, const int* __restrict__ cursor,
                            int* __restrict__ wrel, int nbE, int R) {
  int r = threadIdx.x;
  if (r >= R) return;
  int tot = prefE[(r + 1) * nbE] - prefE[r * nbE];
  int w0 = cursor[r] >> 6;                  // padded segments are SEG-aligned
  int nw = (tot + SEG - 1) >> 6;
  for (int w = 0; w < nw; ++w) wrel[w0 + w] = r;
}

// ---- counting-sort scatter: block bases precomputed (no cursor atomics) ----
// eidx[pos]={src,jd}. Pads stay 0xFF (src=jd=-1). relrow is written by msg.
__global__ __launch_bounds__(256) void scatter_kernel(
    const int* __restrict__ src, const int* __restrict__ dst, const int* __restrict__ et,
    const int* __restrict__ cursor, const int* __restrict__ prefE,
    int* __restrict__ cur2, int2* __restrict__ eidx,
    int E, int R, int nbE) {
  __shared__ int lh[128];
  __shared__ int lbase[128];
  int t = threadIdx.x, b = blockIdx.x;
  if (t < R) {
    lh[t] = 0;
    lbase[t] = cursor[t] + prefE[t * nbE + b] - prefE[t * nbE];
  }
  __syncthreads();
  int e = b * 256 + t;
  if (e < E) {
    int r = et[e], s = src[e], d = dst[e];
    int lr = atomicAdd(&lh[r], 1);          // within-block rank (LDS)
    int jd = atomicAdd(&cur2[d], 1);        // dst-sorted msg row (distributed)
    int pos = lbase[r] + lr;
    eidx[pos] = make_int2(s, jd);
  }
}

// ---- fp32 -> bf16 convert (node features) ----
__global__ __launch_bounds__(256) void cvt_x_kernel(
    const float* __restrict__ x, unsigned short* __restrict__ xb, int n) {
  int i = blockIdx.x * 256 + threadIdx.x;
  if (i < n) xb[i] = f2bf(x[i]);
}

// ---- W[k][n] fp32 -> WT[n][k] bf16 (per 64x64 block; works for W[R] and Wl) ----
__global__ __launch_bounds__(256) void cvt_w_kernel(
    const float* __restrict__ W, unsigned short* __restrict__ WT, int total) {
  int i = blockIdx.x * 256 + threadIdx.x;
  if (i >= total) return;
  int n = i & 63, k = (i >> 6) & 63, r = i >> 12;
  WT[(r << 12) + (n << 6) + k] = f2bf(W[(r << 12) + (k << 6) + n]);
}

// ---- Phase A: MFMA matvec, stream raw msgs (packed bf16) + relrow[jd]=r ----
// msg row layout (32 dwords): dword o<16 = cols (o, o+16); o>=16 = cols (o+16, o+32).
__global__ __launch_bounds__(256) __attribute__((amdgpu_waves_per_eu(1, 4)))
void msg_kernel(const unsigned short* __restrict__ xb,
                const unsigned short* __restrict__ WT,
                const int2* __restrict__ eidx, const int* __restrict__ wrel,
                unsigned int* __restrict__ msgp, int* __restrict__ relrow, int nwaves) {
  const int lane = (int)threadIdx.x & 63;
  const int l15 = lane & 15;
  const int q = lane >> 4;
  const int wave = blockIdx.x * 4 + ((int)threadIdx.x >> 6);
  if (wave >= nwaves) return;
  const long base = (long)wave * SEG;
  const int r = wrel[wave];                 // wave-uniform relation (0 for pad tail)
  const unsigned short* wb = WT + ((long)r << 12);
  bf16x8 Bf[4][2];
#pragma unroll
  for (int nt = 0; nt < 4; ++nt)
#pragma unroll
    for (int kh = 0; kh < 2; ++kh)
      Bf[nt][kh] = *(const bf16x8*)(wb + (nt * 16 + l15) * 64 + kh * 32 + q * 8);
#pragma unroll
  for (int t = 0; t < 4; ++t) {
    int2 rec = eidx[base + t * 16 + l15];
    // rel metadata for agg: row jd's line is owned by this wave anyway
    if (lane < 16 && rec.y >= 0) relrow[rec.y] = r;
    const unsigned short* xr = xb + ((long)max(rec.x, 0) << 6);
    bf16x8 A0 = *(const bf16x8*)(xr + q * 8);
    bf16x8 A1 = *(const bf16x8*)(xr + 32 + q * 8);
    f32x4 acc0 = (f32x4)0.0f, acc1 = (f32x4)0.0f, acc2 = (f32x4)0.0f, acc3 = (f32x4)0.0f;
    acc0 = __builtin_amdgcn_mfma_f32_16x16x32_bf16(A0, Bf[0][0], acc0, 0, 0, 0);
    acc0 = __builtin_amdgcn_mfma_f32_16x16x32_bf16(A1, Bf[0][1], acc0, 0, 0, 0);
    acc1 = __builtin_amdgcn_mfma_f32_16x16x32_bf16(A0, Bf[1][0], acc1, 0, 0, 0);
    acc1 = __builtin_amdgcn_mfma_f32_16x16x32_bf16(A1, Bf[1][1], acc1, 0, 0, 0);
    acc2 = __builtin_amdgcn_mfma_f32_16x16x32_bf16(A0, Bf[2][0], acc2, 0, 0, 0);
    acc2 = __builtin_amdgcn_mfma_f32_16x16x32_bf16(A1, Bf[2][1], acc2, 0, 0, 0);
    acc3 = __builtin_amdgcn_mfma_f32_16x16x32_bf16(A0, Bf[3][0], acc3, 0, 0, 0);
    acc3 = __builtin_amdgcn_mfma_f32_16x16x32_bf16(A1, Bf[3][1], acc3, 0, 0, 0);
#pragma unroll
    for (int rg = 0; rg < 4; ++rg) {
      int row = q * 4 + rg;                  // C/D row = edge within tile
      int jd = __shfl(rec.y, row);           // dst-sorted msg row id (-1 = pad)
      if (jd >= 0) {
        unsigned p0 = (unsigned)f2bf(acc0[rg]) | ((unsigned)f2bf(acc1[rg]) << 16);
        unsigned p1 = (unsigned)f2bf(acc2[rg]) | ((unsigned)f2bf(acc3[rg]) << 16);
        unsigned int* mp = msgp + (long)jd * 32;
        mp[l15] = p0;
        mp[16 + l15] = p1;
      }
    }
  }
}

// ---- Phase B: wave per dst; per-(dst,rel) counts derived locally in LDS ----
__global__ __launch_bounds__(256) void agg_kernel(
    const unsigned int* __restrict__ msgp, const int* __restrict__ dstoff,
    const int* __restrict__ relrow, float* __restrict__ agg, int N) {
  __shared__ int rsh[4][256];
  __shared__ float fsh[4][256];
  const int wv = (int)threadIdx.x >> 6;
  const int lane = (int)threadIdx.x & 63;
  const int j = lane & 31;
  const int half = lane >> 5;
  const int d = blockIdx.x * 4 + wv;
  if (d >= N) return;
  const int off = dstoff[d], end = dstoff[d + 1];
  const int deg = end - off;
  float aLo = 0.f, aHi = 0.f;
  if (deg > 0 && deg <= 256) {
    const int nit = (deg + 63) >> 6;
    int cl[4];
    for (int it = 0; it < nit; ++it) {
      int l = it * 64 + lane;
      if (l < deg) rsh[wv][l] = relrow[off + l];
    }
    __threadfence_block();
    for (int it = 0; it < nit; ++it) {
      int l = it * 64 + lane;
      if (l < deg) {
        int rv = rsh[wv][l];
        int c = 0;
        for (int m = 0; m < deg; ++m) c += (rsh[wv][m] == rv) ? 1 : 0;
        cl[it] = c;
      }
    }
    for (int it = 0; it < nit; ++it) {
      int l = it * 64 + lane;
      if (l < deg) fsh[wv][l] = 1.0f / (float)cl[it];
    }
    __threadfence_block();
    float a0 = 0.f, a1 = 0.f, b0 = 0.f, b1 = 0.f;
    int i = off + half;
    for (; i + 2 < end; i += 4) {
      float w0 = fsh[wv][i - off];
      float w1 = fsh[wv][i + 2 - off];
      unsigned u0 = msgp[(long)i * 32 + j];
      unsigned u1 = msgp[(long)(i + 2) * 32 + j];
      a0 = fmaf(w0, bflo(u0), a0);
      a1 = fmaf(w0, bfhi(u0), a1);
      b0 = fmaf(w1, bflo(u1), b0);
      b1 = fmaf(w1, bfhi(u1), b1);
    }
    if (i < end) {
      float w0 = fsh[wv][i - off];
      unsigned u0 = msgp[(long)i * 32 + j];
      a0 = fmaf(w0, bflo(u0), a0);
      a1 = fmaf(w0, bfhi(u0), a1);
    }
    aLo = a0 + b0;
    aHi = a1 + b1;
  } else if (deg > 256) {
    for (int i = off + half; i < end; i += 2) {
      int rv = relrow[i];
      int c = 0;
      for (int m = off; m < end; ++m) c += (relrow[m] == rv) ? 1 : 0;
      float w = 1.0f / (float)c;
      unsigned u0 = msgp[(long)i * 32 + j];
      aLo = fmaf(w, bflo(u0), aLo);
      aHi = fmaf(w, bfhi(u0), aHi);
    }
  }
  aLo += __shfl_xor(aLo, 32);
  aHi += __shfl_xor(aHi, 32);
  if (half == 0) {
    int colLo = (j < 16) ? j : j + 16;       // cols {0..15, 32..47}
    agg[(long)d * D + colLo] = aLo;
    agg[(long)d * D + colLo + 16] = aHi;     // cols {16..31, 48..63}
  }
}

// ---- self-loop as MFMA GEMM: out = relu(agg + xb @ Wl), agg as C-operand ----
__global__ __launch_bounds__(256) void selfloop_kernel(
    const unsigned short* __restrict__ xbin, const unsigned short* __restrict__ WTl,
    const float* __restrict__ agg, float* __restrict__ out,
    unsigned short* __restrict__ hb, int N) {
  const int lane = (int)threadIdx.x & 63;
  const int l15 = lane & 15;
  const int q = lane >> 4;
  const int wave = blockIdx.x * 4 + ((int)threadIdx.x >> 6);
  const int base = wave * 64;
  if (base >= N) return;
  bf16x8 Bf[4][2];
#pragma unroll
  for (int nt = 0; nt < 4; ++nt)
#pragma unroll
    for (int kh = 0; kh < 2; ++kh)
      Bf[nt][kh] = *(const bf16x8*)(WTl + (nt * 16 + l15) * 64 + kh * 32 + q * 8);
#pragma unroll
  for (int t = 0; t < 4; ++t) {
    const int row0 = base + t * 16;
    if (row0 >= N) break;
    const int m = min(row0 + l15, N - 1);
    const unsigned short* xr = xbin + ((long)m << 6);
    bf16x8 A0 = *(const bf16x8*)(xr + q * 8);
    bf16x8 A1 = *(const bf16x8*)(xr + 32 + q * 8);
    f32x4 acc[4];
#pragma unroll
    for (int nt = 0; nt < 4; ++nt) {
#pragma unroll
      for (int rg = 0; rg < 4; ++rg) {
        int node = row0 + q * 4 + rg;
        acc[nt][rg] = (node < N) ? agg[(long)node * D + nt * 16 + l15] : 0.0f;
      }
    }
#pragma unroll
    for (int nt = 0; nt < 4; ++nt) {
      acc[nt] = __builtin_amdgcn_mfma_f32_16x16x32_bf16(A0, Bf[nt][0], acc[nt], 0, 0, 0);
      acc[nt] = __builtin_amdgcn_mfma_f32_16x16x32_bf16(A1, Bf[nt][1], acc[nt], 0, 0, 0);
    }
#pragma unroll
    for (int rg = 0; rg < 4; ++rg) {
      int node = row0 + q * 4 + rg;
      if (node < N) {
#pragma unroll
        for (int nt = 0; nt < 4; ++nt) {
          float v = fmaxf(acc[nt][rg], 0.0f);
          out[(long)node * D + nt * 16 + l15] = v;
          if (hb) hb[(long)node * D + nt * 16 + l15] = f2bf(v);
        }
      }
    }
  }
}

extern "C" void kernel_launch(void* const* d_in, const int* in_sizes, int n_in,
                              void* d_out, int out_size, void* d_ws, size_t ws_size,
                              hipStream_t stream) {
  const float* x   = (const float*)d_in[0];
  const int* src   = (const int*)d_in[1];
  const int* dst   = (const int*)d_in[2];
  const int* et    = (const int*)d_in[3];
  const float* W1  = (const float*)d_in[4];
  const float* Wl1 = (const float*)d_in[5];
  const float* W2  = (const float*)d_in[6];
  const float* Wl2 = (const float*)d_in[7];
  float* out = (float*)d_out;

  const int N = in_sizes[0] / D;
  const int E = in_sizes[1];
  const int R = in_sizes[4] / (D * D);

  const int Ecap = ((E + SEG - 1) & ~(SEG - 1)) + R * SEG;
  const int nwaves = Ecap / SEG;
  const int nbN = (N + 255) / 256;          // blocks over nodes
  const int nbE = (E + 255) / 256;          // blocks over edges
  const int nBC = R * nbE;                  // bcnt length
  const int nbBC = (nBC + 255) / 256;       // scan blocks over bcnt
  const int nbMax = (nbBC > nbN) ? nbBC : nbN;

  char* ws = (char*)d_ws;
  size_t off = 0;
  auto alloc = [&](size_t bytes) -> void* {
    void* p = (void*)(ws + off);
    off += (bytes + 255) & ~(size_t)255;
    return p;
  };
  int*   cursor = (int*)alloc((size_t)R * sizeof(int));
  int*   deg    = (int*)alloc((size_t)N * sizeof(int));
  int*   bcnt   = (int*)alloc((size_t)nBC * sizeof(int));
  int*   prefE  = (int*)alloc((size_t)(nBC + 1) * sizeof(int));
  int*   bsum   = (int*)alloc((size_t)nbMax * sizeof(int));
  int*   dstoff = (int*)alloc((size_t)(N + 1) * sizeof(int));
  int*   cur2   = (int*)alloc((size_t)N * sizeof(int));
  int*   relrow = (int*)alloc((size_t)E * sizeof(int));
  int*   wrel   = (int*)alloc((size_t)nwaves * sizeof(int));
  int2*  eidx   = (int2*)alloc((size_t)(Ecap + SEG) * sizeof(int2));
  unsigned int* msgp = (unsigned int*)alloc((size_t)E * 32 * sizeof(unsigned int));
  float* agg    = (float*)alloc((size_t)N * D * sizeof(float));
  unsigned short* xb  = (unsigned short*)alloc((size_t)N * D * sizeof(unsigned short));
  unsigned short* hb  = (unsigned short*)alloc((size_t)N * D * sizeof(unsigned short));
  unsigned short* WT1 = (unsigned short*)alloc((size_t)R * D * D * sizeof(unsigned short));
  unsigned short* WT2 = (unsigned short*)alloc((size_t)R * D * D * sizeof(unsigned short));
  unsigned short* WTl1 = (unsigned short*)alloc((size_t)D * D * sizeof(unsigned short));
  unsigned short* WTl2 = (unsigned short*)alloc((size_t)D * D * sizeof(unsigned short));
  (void)ws_size; (void)n_in; (void)out_size;

  const int msg_blocks = (nwaves + 3) / 4;
  const int agg_blocks = (N + 3) / 4;
  const int sl_waves = (N + 63) / 64;
  const int sl_blocks = (sl_waves + 3) / 4;
  const int wtot = R * D * D;

  // ---- shared preprocessing ----
  hipMemsetAsync(deg, 0, (size_t)N * sizeof(int), stream);
  hipMemsetAsync(wrel, 0, (size_t)nwaves * sizeof(int), stream);
  hipMemsetAsync(eidx, 0xFF, (size_t)(Ecap + SEG) * sizeof(int2), stream);
  count_kernel<<<nbE, 256, 0, stream>>>(dst, et, bcnt, deg, E, R, nbE);
  // scan bcnt -> prefE (per-(rel,block) exclusive bases)
  scanA_kernel<<<nbBC, 256, 0, stream>>>(bcnt, bsum, nBC);
  scanB_kernel<<<1, 256, 0, stream>>>(bsum, nbBC);
  scanC_pref_kernel<<<nbBC, 256, 0, stream>>>(bcnt, bsum, prefE, nBC);
  prefix_kernel<<<1, 128, 0, stream>>>(prefE, cursor, nbE, R);
  wrel_kernel<<<1, 128, 0, stream>>>(prefE, cursor, wrel, nbE, R);
  // scan deg -> dstoff / cur2
  scanA_kernel<<<nbN, 256, 0, stream>>>(deg, bsum, N);
  scanB_kernel<<<1, 256, 0, stream>>>(bsum, nbN);
  scanC_deg_kernel<<<nbN, 256, 0, stream>>>(deg, bsum, dstoff, cur2, N);
  scatter_kernel<<<nbE, 256, 0, stream>>>(src, dst, et, cursor, prefE, cur2,
                                          eidx, E, R, nbE);
  cvt_x_kernel<<<(N * D + 255) / 256, 256, 0, stream>>>(x, xb, N * D);
  cvt_w_kernel<<<(wtot + 255) / 256, 256, 0, stream>>>(W1, WT1, wtot);
  cvt_w_kernel<<<(wtot + 255) / 256, 256, 0, stream>>>(W2, WT2, wtot);
  cvt_w_kernel<<<(D * D + 255) / 256, 256, 0, stream>>>(Wl1, WTl1, D * D);
  cvt_w_kernel<<<(D * D + 255) / 256, 256, 0, stream>>>(Wl2, WTl2, D * D);

  // ---- layer 1 ----
  msg_kernel<<<msg_blocks, 256, 0, stream>>>(xb, WT1, eidx, wrel, msgp, relrow, nwaves);
  agg_kernel<<<agg_blocks, 256, 0, stream>>>(msgp, dstoff, relrow, agg, N);
  selfloop_kernel<<<sl_blocks, 256, 0, stream>>>(xb, WTl1, agg, out, hb, N);

  // ---- layer 2 ----
  msg_kernel<<<msg_blocks, 256, 0, stream>>>(hb, WT2, eidx, wrel, msgp, relrow, nwaves);
  agg_kernel<<<agg_blocks, 256, 0, stream>>>(msgp, dstoff, relrow, agg, N);
  selfloop_kernel<<<sl_blocks, 256, 0, stream>>>(hb, WTl2, agg, out, nullptr, N);
}

// Round 11
// 364.005 us; speedup vs baseline: 1.0301x; 1.0301x over previous
//
#include <hip/hip_runtime.h>

typedef __attribute__((ext_vector_type(8))) short bf16x8;
typedef __attribute__((ext_vector_type(4))) float f32x4;

#define RFL(v) __builtin_amdgcn_readfirstlane(v)

constexpr int D = 64;
constexpr int SEG = 64;    // relation-segment padding granule = edges per wave
constexpr int CSTR = 16;   // counter stride (ints): 1 atomic counter per 64B line

__device__ inline unsigned short f2bf(float f) {  // RNE fp32->bf16
  unsigned u = __float_as_uint(f);
  u += 0x7fff + ((u >> 16) & 1);
  return (unsigned short)(u >> 16);
}
__device__ inline float bflo(unsigned u) { return __uint_as_float(u << 16); }
__device__ inline float bfhi(unsigned u) { return __uint_as_float(u & 0xffff0000u); }

// ---- counting: per-block relation histogram -> bcnt[r*nbE+b]; padded deg ----
__global__ __launch_bounds__(256) void count_kernel(
    const int* __restrict__ dst, const int* __restrict__ et,
    int* __restrict__ bcnt, int* __restrict__ deg, int E, int R, int nbE) {
  __shared__ int lh[128];
  int t = threadIdx.x;
  if (t < 128) lh[t] = 0;
  __syncthreads();
  int e = blockIdx.x * 256 + t;
  if (e < E) {
    atomicAdd(&deg[(long)dst[e] * CSTR], 1);   // one counter per cache line
    atomicAdd(&lh[et[e]], 1);
  }
  __syncthreads();
  if (t < R) bcnt[t * nbE + blockIdx.x] = lh[t];
}

// ---- generic 3-phase exclusive scan (elem stride for padded arrays) ----
__global__ __launch_bounds__(256) void scanA_kernel(
    const int* __restrict__ arr, int* __restrict__ bsum, int n, int stride) {
  __shared__ int s[256];
  int t = threadIdx.x;
  int i = blockIdx.x * 256 + t;
  s[t] = (i < n) ? arr[(long)i * stride] : 0;
  __syncthreads();
  for (int o = 128; o > 0; o >>= 1) {
    if (t < o) s[t] += s[t + o];
    __syncthreads();
  }
  if (t == 0) bsum[blockIdx.x] = s[0];
}

__global__ __launch_bounds__(256) void scanB_kernel(int* __restrict__ bsum, int nb) {
  __shared__ int s[256];
  __shared__ int carry;
  int t = threadIdx.x;
  if (t == 0) carry = 0;
  __syncthreads();
  for (int base = 0; base < nb; base += 256) {
    int i = base + t;
    int v = (i < nb) ? bsum[i] : 0;
    s[t] = v;
    __syncthreads();
    for (int o = 1; o < 256; o <<= 1) {
      int u = (t >= o) ? s[t - o] : 0;
      __syncthreads();
      s[t] += u;
      __syncthreads();
    }
    if (i < nb) bsum[i] = carry + s[t] - v;   // exclusive
    __syncthreads();
    if (t == 0) carry += s[255];
    __syncthreads();
  }
}

// writes pref[i] (exclusive) and pref[n] = total  (dense arrays)
__global__ __launch_bounds__(256) void scanC_pref_kernel(
    const int* __restrict__ arr, const int* __restrict__ bsum,
    int* __restrict__ pref, int n) {
  __shared__ int s[256];
  int t = threadIdx.x;
  int i = blockIdx.x * 256 + t;
  int v = (i < n) ? arr[i] : 0;
  s[t] = v;
  __syncthreads();
  for (int o = 1; o < 256; o <<= 1) {
    int u = (t >= o) ? s[t - o] : 0;
    __syncthreads();
    s[t] += u;
    __syncthreads();
  }
  int excl = bsum[blockIdx.x] + s[t] - v;
  if (i < n) pref[i] = excl;
  if (i == n - 1) pref[n] = excl + v;
}

// deg variant: strided deg in, dense dstoff out, padded cur2 working copy
__global__ __launch_bounds__(256) void scanC_deg_kernel(
    const int* __restrict__ deg, const int* __restrict__ bsum,
    int* __restrict__ dstoff, int* __restrict__ cur2, int N) {
  __shared__ int s[256];
  int t = threadIdx.x;
  int i = blockIdx.x * 256 + t;
  int v = (i < N) ? deg[(long)i * CSTR] : 0;
  s[t] = v;
  __syncthreads();
  for (int o = 1; o < 256; o <<= 1) {
    int u = (t >= o) ? s[t - o] : 0;
    __syncthreads();
    s[t] += u;
    __syncthreads();
  }
  int excl = bsum[blockIdx.x] + s[t] - v;
  if (i < N) { dstoff[i] = excl; cur2[(long)i * CSTR] = excl; }
  if (i == N - 1) dstoff[N] = excl + v;
}

// ---- padded relation cursors from bcnt-scan boundary values ----
__global__ void prefix_kernel(const int* __restrict__ prefE,
                              int* __restrict__ cursor, int nbE, int R) {
  __shared__ int sc[128];
  int l = threadIdx.x;
  int c = 0;
  if (l < R) {
    int tot = prefE[(l + 1) * nbE] - prefE[l * nbE];
    c = (tot + SEG - 1) & ~(SEG - 1);
  }
  sc[l] = c;
  __syncthreads();
  for (int ofs = 1; ofs < 128; ofs <<= 1) {
    int v = (l >= ofs) ? sc[l - ofs] : 0;
    __syncthreads();
    sc[l] += v;
    __syncthreads();
  }
  if (l < R) cursor[l] = sc[l] - c;
}

// ---- wave -> relation table (wave-uniform lookup for msg_kernel) ----
__global__ void wrel_kernel(const int* __restrict__ prefE, const int* __restrict__ cursor,
                            int* __restrict__ wrel, int nbE, int R) {
  int r = threadIdx.x;
  if (r >= R) return;
  int tot = prefE[(r + 1) * nbE] - prefE[r * nbE];
  int w0 = cursor[r] >> 6;                  // padded segments are SEG-aligned
  int nw = (tot + SEG - 1) >> 6;
  for (int w = 0; w < nw; ++w) wrel[w0 + w] = r;
}

// ---- counting-sort scatter: block bases precomputed; padded cur2 atomics ----
// eidx[pos]={src,jd}. Pads stay 0xFF (src=jd=-1). relrow written by msg L1.
__global__ __launch_bounds__(256) void scatter_kernel(
    const int* __restrict__ src, const int* __restrict__ dst, const int* __restrict__ et,
    const int* __restrict__ cursor, const int* __restrict__ prefE,
    int* __restrict__ cur2, int2* __restrict__ eidx,
    int E, int R, int nbE) {
  __shared__ int lh[128];
  __shared__ int lbase[128];
  int t = threadIdx.x, b = blockIdx.x;
  if (t < R) {
    lh[t] = 0;
    lbase[t] = cursor[t] + prefE[t * nbE + b] - prefE[t * nbE];
  }
  __syncthreads();
  int e = b * 256 + t;
  if (e < E) {
    int r = et[e], s = src[e], d = dst[e];
    int lr = atomicAdd(&lh[r], 1);               // within-block rank (LDS)
    int jd = atomicAdd(&cur2[(long)d * CSTR], 1); // own line -> pipelined RMW
    int pos = lbase[r] + lr;
    eidx[pos] = make_int2(s, jd);
  }
}

// ---- fp32 -> bf16 convert (node features) ----
__global__ __launch_bounds__(256) void cvt_x_kernel(
    const float* __restrict__ x, unsigned short* __restrict__ xb, int n) {
  int i = blockIdx.x * 256 + threadIdx.x;
  if (i < n) xb[i] = f2bf(x[i]);
}

// ---- W[k][n] fp32 -> WT[n][k] bf16 (per 64x64 block; works for W[R] and Wl) ----
__global__ __launch_bounds__(256) void cvt_w_kernel(
    const float* __restrict__ W, unsigned short* __restrict__ WT, int total) {
  int i = blockIdx.x * 256 + threadIdx.x;
  if (i >= total) return;
  int n = i & 63, k = (i >> 6) & 63, r = i >> 12;
  WT[(r << 12) + (n << 6) + k] = f2bf(W[(r << 12) + (k << 6) + n]);
}

// ---- Phase A: MFMA matvec, stream raw msgs; relrow only when non-null ----
// msg row layout (32 dwords): dword o<16 = cols (o, o+16); o>=16 = cols (o+16, o+32).
__global__ __launch_bounds__(256) __attribute__((amdgpu_waves_per_eu(1, 4)))
void msg_kernel(const unsigned short* __restrict__ xb,
                const unsigned short* __restrict__ WT,
                const int2* __restrict__ eidx, const int* __restrict__ wrel,
                unsigned int* __restrict__ msgp, int* __restrict__ relrow, int nwaves) {
  const int lane = (int)threadIdx.x & 63;
  const int l15 = lane & 15;
  const int q = lane >> 4;
  const int wave = blockIdx.x * 4 + ((int)threadIdx.x >> 6);
  if (wave >= nwaves) return;
  const long base = (long)wave * SEG;
  const int r = wrel[wave];                 // wave-uniform relation (0 for pad tail)
  const unsigned short* wb = WT + ((long)r << 12);
  bf16x8 Bf[4][2];
#pragma unroll
  for (int nt = 0; nt < 4; ++nt)
#pragma unroll
    for (int kh = 0; kh < 2; ++kh)
      Bf[nt][kh] = *(const bf16x8*)(wb + (nt * 16 + l15) * 64 + kh * 32 + q * 8);
#pragma unroll
  for (int t = 0; t < 4; ++t) {
    int2 rec = eidx[base + t * 16 + l15];
    if (relrow && lane < 16 && rec.y >= 0) relrow[rec.y] = r;  // graph-invariant: L1 only
    const unsigned short* xr = xb + ((long)max(rec.x, 0) << 6);
    bf16x8 A0 = *(const bf16x8*)(xr + q * 8);
    bf16x8 A1 = *(const bf16x8*)(xr + 32 + q * 8);
    f32x4 acc0 = (f32x4)0.0f, acc1 = (f32x4)0.0f, acc2 = (f32x4)0.0f, acc3 = (f32x4)0.0f;
    acc0 = __builtin_amdgcn_mfma_f32_16x16x32_bf16(A0, Bf[0][0], acc0, 0, 0, 0);
    acc0 = __builtin_amdgcn_mfma_f32_16x16x32_bf16(A1, Bf[0][1], acc0, 0, 0, 0);
    acc1 = __builtin_amdgcn_mfma_f32_16x16x32_bf16(A0, Bf[1][0], acc1, 0, 0, 0);
    acc1 = __builtin_amdgcn_mfma_f32_16x16x32_bf16(A1, Bf[1][1], acc1, 0, 0, 0);
    acc2 = __builtin_amdgcn_mfma_f32_16x16x32_bf16(A0, Bf[2][0], acc2, 0, 0, 0);
    acc2 = __builtin_amdgcn_mfma_f32_16x16x32_bf16(A1, Bf[2][1], acc2, 0, 0, 0);
    acc3 = __builtin_amdgcn_mfma_f32_16x16x32_bf16(A0, Bf[3][0], acc3, 0, 0, 0);
    acc3 = __builtin_amdgcn_mfma_f32_16x16x32_bf16(A1, Bf[3][1], acc3, 0, 0, 0);
#pragma unroll
    for (int rg = 0; rg < 4; ++rg) {
      int row = q * 4 + rg;                  // C/D row = edge within tile
      int jd = __shfl(rec.y, row);           // dst-sorted msg row id (-1 = pad)
      if (jd >= 0) {
        unsigned p0 = (unsigned)f2bf(acc0[rg]) | ((unsigned)f2bf(acc1[rg]) << 16);
        unsigned p1 = (unsigned)f2bf(acc2[rg]) | ((unsigned)f2bf(acc3[rg]) << 16);
        unsigned int* mp = msgp + (long)jd * 32;
        mp[l15] = p0;
        mp[16 + l15] = p1;
      }
    }
  }
}

// ---- Phase B: wave per dst; per-(dst,rel) counts derived locally in LDS ----
__global__ __launch_bounds__(256) void agg_kernel(
    const unsigned int* __restrict__ msgp, const int* __restrict__ dstoff,
    const int* __restrict__ relrow, float* __restrict__ agg, int N) {
  __shared__ int rsh[4][256];
  __shared__ float fsh[4][256];
  const int wv = (int)threadIdx.x >> 6;
  const int lane = (int)threadIdx.x & 63;
  const int j = lane & 31;
  const int half = lane >> 5;
  const int d = blockIdx.x * 4 + wv;
  if (d >= N) return;
  const int off = dstoff[d], end = dstoff[d + 1];
  const int deg = end - off;
  float aLo = 0.f, aHi = 0.f;
  if (deg > 0 && deg <= 256) {
    const int nit = (deg + 63) >> 6;
    int cl[4];
    for (int it = 0; it < nit; ++it) {
      int l = it * 64 + lane;
      if (l < deg) rsh[wv][l] = relrow[off + l];
    }
    __threadfence_block();
    for (int it = 0; it < nit; ++it) {
      int l = it * 64 + lane;
      if (l < deg) {
        int rv = rsh[wv][l];
        int c = 0;
        for (int m = 0; m < deg; ++m) c += (rsh[wv][m] == rv) ? 1 : 0;
        cl[it] = c;
      }
    }
    for (int it = 0; it < nit; ++it) {
      int l = it * 64 + lane;
      if (l < deg) fsh[wv][l] = 1.0f / (float)cl[it];
    }
    __threadfence_block();
    float a0 = 0.f, a1 = 0.f, b0 = 0.f, b1 = 0.f;
    int i = off + half;
    for (; i + 2 < end; i += 4) {
      float w0 = fsh[wv][i - off];
      float w1 = fsh[wv][i + 2 - off];
      unsigned u0 = msgp[(long)i * 32 + j];
      unsigned u1 = msgp[(long)(i + 2) * 32 + j];
      a0 = fmaf(w0, bflo(u0), a0);
      a1 = fmaf(w0, bfhi(u0), a1);
      b0 = fmaf(w1, bflo(u1), b0);
      b1 = fmaf(w1, bfhi(u1), b1);
    }
    if (i < end) {
      float w0 = fsh[wv][i - off];
      unsigned u0 = msgp[(long)i * 32 + j];
      a0 = fmaf(w0, bflo(u0), a0);
      a1 = fmaf(w0, bfhi(u0), a1);
    }
    aLo = a0 + b0;
    aHi = a1 + b1;
  } else if (deg > 256) {
    for (int i = off + half; i < end; i += 2) {
      int rv = relrow[i];
      int c = 0;
      for (int m = off; m < end; ++m) c += (relrow[m] == rv) ? 1 : 0;
      float w = 1.0f / (float)c;
      unsigned u0 = msgp[(long)i * 32 + j];
      aLo = fmaf(w, bflo(u0), aLo);
      aHi = fmaf(w, bfhi(u0), aHi);
    }
  }
  aLo += __shfl_xor(aLo, 32);
  aHi += __shfl_xor(aHi, 32);
  if (half == 0) {
    int colLo = (j < 16) ? j : j + 16;       // cols {0..15, 32..47}
    agg[(long)d * D + colLo] = aLo;
    agg[(long)d * D + colLo + 16] = aHi;     // cols {16..31, 48..63}
  }
}

// ---- self-loop as MFMA GEMM: out = relu(agg + xb @ Wl), agg as C-operand ----
__global__ __launch_bounds__(256) void selfloop_kernel(
    const unsigned short* __restrict__ xbin, const unsigned short* __restrict__ WTl,
    const float* __restrict__ agg, float* __restrict__ out,
    unsigned short* __restrict__ hb, int N) {
  const int lane = (int)threadIdx.x & 63;
  const int l15 = lane & 15;
  const int q = lane >> 4;
  const int wave = blockIdx.x * 4 + ((int)threadIdx.x >> 6);
  const int base = wave * 64;
  if (base >= N) return;
  bf16x8 Bf[4][2];
#pragma unroll
  for (int nt = 0; nt < 4; ++nt)
#pragma unroll
    for (int kh = 0; kh < 2; ++kh)
      Bf[nt][kh] = *(const bf16x8*)(WTl + (nt * 16 + l15) * 64 + kh * 32 + q * 8);
#pragma unroll
  for (int t = 0; t < 4; ++t) {
    const int row0 = base + t * 16;
    if (row0 >= N) break;
    const int m = min(row0 + l15, N - 1);
    const unsigned short* xr = xbin + ((long)m << 6);
    bf16x8 A0 = *(const bf16x8*)(xr + q * 8);
    bf16x8 A1 = *(const bf16x8*)(xr + 32 + q * 8);
    f32x4 acc[4];
#pragma unroll
    for (int nt = 0; nt < 4; ++nt) {
#pragma unroll
      for (int rg = 0; rg < 4; ++rg) {
        int node = row0 + q * 4 + rg;
        acc[nt][rg] = (node < N) ? agg[(long)node * D + nt * 16 + l15] : 0.0f;
      }
    }
#pragma unroll
    for (int nt = 0; nt < 4; ++nt) {
      acc[nt] = __builtin_amdgcn_mfma_f32_16x16x32_bf16(A0, Bf[nt][0], acc[nt], 0, 0, 0);
      acc[nt] = __builtin_amdgcn_mfma_f32_16x16x32_bf16(A1, Bf[nt][1], acc[nt], 0, 0, 0);
    }
#pragma unroll
    for (int rg = 0; rg < 4; ++rg) {
      int node = row0 + q * 4 + rg;
      if (node < N) {
#pragma unroll
        for (int nt = 0; nt < 4; ++nt) {
          float v = fmaxf(acc[nt][rg], 0.0f);
          out[(long)node * D + nt * 16 + l15] = v;
          if (hb) hb[(long)node * D + nt * 16 + l15] = f2bf(v);
        }
      }
    }
  }
}

extern "C" void kernel_launch(void* const* d_in, const int* in_sizes, int n_in,
                              void* d_out, int out_size, void* d_ws, size_t ws_size,
                              hipStream_t stream) {
  const float* x   = (const float*)d_in[0];
  const int* src   = (const int*)d_in[1];
  const int* dst   = (const int*)d_in[2];
  const int* et    = (const int*)d_in[3];
  const float* W1  = (const float*)d_in[4];
  const float* Wl1 = (const float*)d_in[5];
  const float* W2  = (const float*)d_in[6];
  const float* Wl2 = (const float*)d_in[7];
  float* out = (float*)d_out;

  const int N = in_sizes[0] / D;
  const int E = in_sizes[1];
  const int R = in_sizes[4] / (D * D);

  const int Ecap = ((E + SEG - 1) & ~(SEG - 1)) + R * SEG;
  const int nwaves = Ecap / SEG;
  const int nbN = (N + 255) / 256;          // blocks over nodes
  const int nbE = (E + 255) / 256;          // blocks over edges
  const int nBC = R * nbE;                  // bcnt length
  const int nbBC = (nBC + 255) / 256;       // scan blocks over bcnt
  const int nbMax = (nbBC > nbN) ? nbBC : nbN;

  char* ws = (char*)d_ws;
  size_t off = 0;
  auto alloc = [&](size_t bytes) -> void* {
    void* p = (void*)(ws + off);
    off += (bytes + 255) & ~(size_t)255;
    return p;
  };
  int*   cursor = (int*)alloc((size_t)R * sizeof(int));
  int*   deg    = (int*)alloc((size_t)N * CSTR * sizeof(int));   // padded: 1/line
  int*   cur2   = (int*)alloc((size_t)N * CSTR * sizeof(int));   // padded: 1/line
  int*   bcnt   = (int*)alloc((size_t)nBC * sizeof(int));
  int*   prefE  = (int*)alloc((size_t)(nBC + 1) * sizeof(int));
  int*   bsum   = (int*)alloc((size_t)nbMax * sizeof(int));
  int*   dstoff = (int*)alloc((size_t)(N + 1) * sizeof(int));
  int*   relrow = (int*)alloc((size_t)E * sizeof(int));
  int*   wrel   = (int*)alloc((size_t)nwaves * sizeof(int));
  int2*  eidx   = (int2*)alloc((size_t)(Ecap + SEG) * sizeof(int2));
  unsigned int* msgp = (unsigned int*)alloc((size_t)E * 32 * sizeof(unsigned int));
  float* agg    = (float*)alloc((size_t)N * D * sizeof(float));
  unsigned short* xb  = (unsigned short*)alloc((size_t)N * D * sizeof(unsigned short));
  unsigned short* hb  = (unsigned short*)alloc((size_t)N * D * sizeof(unsigned short));
  unsigned short* WT1 = (unsigned short*)alloc((size_t)R * D * D * sizeof(unsigned short));
  unsigned short* WT2 = (unsigned short*)alloc((size_t)R * D * D * sizeof(unsigned short));
  unsigned short* WTl1 = (unsigned short*)alloc((size_t)D * D * sizeof(unsigned short));
  unsigned short* WTl2 = (unsigned short*)alloc((size_t)D * D * sizeof(unsigned short));
  (void)ws_size; (void)n_in; (void)out_size;

  const int msg_blocks = (nwaves + 3) / 4;
  const int agg_blocks = (N + 3) / 4;
  const int sl_waves = (N + 63) / 64;
  const int sl_blocks = (sl_waves + 3) / 4;
  const int wtot = R * D * D;

  // ---- shared preprocessing ----
  hipMemsetAsync(deg, 0, (size_t)N * CSTR * sizeof(int), stream);
  hipMemsetAsync(wrel, 0, (size_t)nwaves * sizeof(int), stream);
  hipMemsetAsync(eidx, 0xFF, (size_t)(Ecap + SEG) * sizeof(int2), stream);
  count_kernel<<<nbE, 256, 0, stream>>>(dst, et, bcnt, deg, E, R, nbE);
  // scan bcnt -> prefE (per-(rel,block) exclusive bases)
  scanA_kernel<<<nbBC, 256, 0, stream>>>(bcnt, bsum, nBC, 1);
  scanB_kernel<<<1, 256, 0, stream>>>(bsum, nbBC);
  scanC_pref_kernel<<<nbBC, 256, 0, stream>>>(bcnt, bsum, prefE, nBC);
  prefix_kernel<<<1, 128, 0, stream>>>(prefE, cursor, nbE, R);
  wrel_kernel<<<1, 128, 0, stream>>>(prefE, cursor, wrel, nbE, R);
  // scan deg (padded) -> dstoff / cur2 (padded)
  scanA_kernel<<<nbN, 256, 0, stream>>>(deg, bsum, N, CSTR);
  scanB_kernel<<<1, 256, 0, stream>>>(bsum, nbN);
  scanC_deg_kernel<<<nbN, 256, 0, stream>>>(deg, bsum, dstoff, cur2, N);
  scatter_kernel<<<nbE, 256, 0, stream>>>(src, dst, et, cursor, prefE, cur2,
                                          eidx, E, R, nbE);
  cvt_x_kernel<<<(N * D + 255) / 256, 256, 0, stream>>>(x, xb, N * D);
  cvt_w_kernel<<<(wtot + 255) / 256, 256, 0, stream>>>(W1, WT1, wtot);
  cvt_w_kernel<<<(wtot + 255) / 256, 256, 0, stream>>>(W2, WT2, wtot);
  cvt_w_kernel<<<(D * D + 255) / 256, 256, 0, stream>>>(Wl1, WTl1, D * D);
  cvt_w_kernel<<<(D * D + 255) / 256, 256, 0, stream>>>(Wl2, WTl2, D * D);

  // ---- layer 1 (msg also writes graph-invariant relrow) ----
  msg_kernel<<<msg_blocks, 256, 0, stream>>>(xb, WT1, eidx, wrel, msgp, relrow, nwaves);
  agg_kernel<<<agg_blocks, 256, 0, stream>>>(msgp, dstoff, relrow, agg, N);
  selfloop_kernel<<<sl_blocks, 256, 0, stream>>>(xb, WTl1, agg, out, hb, N);

  // ---- layer 2 (relrow already valid: skip) ----
  msg_kernel<<<msg_blocks, 256, 0, stream>>>(hb, WT2, eidx, wrel, msgp, nullptr, nwaves);
  agg_kernel<<<agg_blocks, 256, 0, stream>>>(msgp, dstoff, relrow, agg, N);
  selfloop_kernel<<<sl_blocks, 256, 0, stream>>>(hb, WTl2, agg, out, nullptr, N);
}